// Round 8
// baseline (132.511 us; speedup 1.0000x reference)
//
#include <hip/hip_runtime.h>
#include <stdint.h>

// OrthogonalLinear: pyramid Givens circuit, n = m = 512, B = 256.
// T = 1021 layers; layer t has gates (i, i+1) for i = (t&1), (t&1)+2, ...,
// i <= min(t, 1020-t). theta index: k = (t+i)/2 + 1, idx = k(k-1)/2 + (k-1-i).
//
// Table W4 (d_ws), float4 units: pair p (layers t=2p, 2p+1) at [p*256,(p+1)*256).
// Quarter q in 0..3, lane L: idx = p*256 + q*64 + L:
//   q0 = (cE0,sE0,cE1,sE1)   even gates at wires 8L+0, 8L+2
//   q1 = (cE2,sE2,cE3,sE3)   even gates at wires 8L+4, 8L+6
//   q2 = (cO0,sO0,cO1,sO1)   odd  gates at wires 8L+1, 8L+3
//   q3 = (cO2,sO2,cU-1,sU)   odd gate at 8L+5; boundary gate (8L+7) stored
//                            as (c-1, s) so DPP's shifted-in 0 = identity.
// Block p=510 (128 float4, q=0/1, plain (c,s)) = final even layer t=1020.
// Total 130688 float4 = 2.09 MB.
//
// R8: circuit processes 2 ROWS PER WAVE (128 blocks x 64 threads). The 4
// 1KB table loads per pair now amortize over 2 rows of compute, and table
// readers per XCD-L2 drop 32 -> 16. Discriminates per-wave-throughput (H1)
// vs L2-same-address-contention (H2) as the source of the ~200 cyc/pair
// memory term seen in R2-R7.

#define N_WIRES 512
#define BATCH   256
#define PAIRS   510
#define PF      10                 // ring depth; 510 = 10 * 51
#define FINAL4  (PAIRS * 256)      // 130560
#define TOTAL4  (FINAL4 + 128)     // 130688
#define TOTAL2  (TOTAL4 * 2)       // 261376 float2 slots

// ---------------- kernel 1: fused table build ----------------
__global__ __launch_bounds__(256) void fused_kernel(
    const float* __restrict__ thetas, float2* __restrict__ W2) {
  int tid = blockIdx.x * 256 + threadIdx.x;
  if (tid >= TOTAL2) return;
  int p = tid >> 9, r = tid & 511;
  int q = r >> 7, L = (r >> 1) & 63, e = r & 1, h = q >> 1;
  int t = 2 * p + h;
  int i = 8 * L + 4 * (q & 1) + 2 * e + h;
  float c = 1.0f, s = 0.0f;
  if (i <= min(t, 1020 - t)) {
    int k = ((t + i) >> 1) + 1;
    int idx = ((k * (k - 1)) >> 1) + (k - 1 - i);
    __sincosf(thetas[idx], &s, &c);
  }
  if (q == 3 && e == 1) c -= 1.0f;   // boundary gate stored as (c-1, s)
  W2[tid] = make_float2(c, s);
}

// ---------------- kernel 2: apply circuit, 2 rows per wave ----------------
template <int N>
__device__ __forceinline__ void wait_vm() {
  asm volatile("s_waitcnt vmcnt(%0)" ::"i"(N) : "memory");
}

__device__ __forceinline__ float dpp_shr1(float v) {  // lane i <- i-1; lane0 <- 0
  return __int_as_float(
      __builtin_amdgcn_mov_dpp(__float_as_int(v), 0x138, 0xF, 0xF, true));
}
__device__ __forceinline__ float dpp_shl1(float v) {  // lane i <- i+1; lane63 <- 0
  return __int_as_float(
      __builtin_amdgcn_mov_dpp(__float_as_int(v), 0x130, 0xF, 0xF, true));
}

// Packed Givens gate: ab=(a,b), cs=(c,s) -> (c*a+s*b, c*b-s*a), 2 VOP3P instr.
__device__ __forceinline__ float2 gate_pk(float2 cs, float2 ab) {
  float2 t, r;
  asm("v_pk_mul_f32 %0, %1, %2 op_sel:[1,1] op_sel_hi:[1,0] neg_hi:[1,0]"
      : "=v"(t)
      : "v"(cs), "v"(ab));
  asm("v_pk_fma_f32 %0, %1, %2, %3 op_sel:[0,0,0] op_sel_hi:[0,1,1]"
      : "=v"(r)
      : "v"(cs), "v"(ab), "v"(t));
  return r;
}

__device__ __forceinline__ void gate_s(float& a, float& b, float c, float s) {
  float na = fmaf(c, a, s * b);
  float nb = fmaf(c, b, -(s * a));
  a = na;
  b = nb;
}

__device__ __forceinline__ void pair_compute(float2& A, float2& B, float2& C,
                                             float2& D, const float4& q0,
                                             const float4& q1, const float4& q2,
                                             const float4& q3) {
  // even layer: 4 packed gates
  A = gate_pk(make_float2(q0.x, q0.y), A);
  B = gate_pk(make_float2(q0.z, q0.w), B);
  C = gate_pk(make_float2(q1.x, q1.y), C);
  D = gate_pk(make_float2(q1.z, q1.w), D);
  // odd layer
  float cl_m1 = dpp_shr1(q3.z);   // left neighbor's (c-1); lane0 -> 0 = identity
  float sl    = dpp_shr1(q3.w);   // lane0 -> 0
  float rv0 = dpp_shl1(A.x);      // right neighbor's wire 8L+8 (post-even)
  float lv7 = dpp_shr1(D.y);      // left neighbor's wire 8L-1 (post-even)
  gate_s(A.y, B.x, q2.x, q2.y);
  gate_s(B.y, C.x, q2.z, q2.w);
  gate_s(C.y, D.x, q3.x, q3.y);
  // boundary: up-gate (8L+7, 8L+8) a-side, c = 1 + q3.z:
  float nv7 = fmaf(q3.w, rv0, fmaf(q3.z, D.y, D.y));
  // down-gate (8L-1, 8L) b-side, c = 1 + cl_m1:
  float nv0 = fmaf(-sl, lv7, fmaf(cl_m1, A.x, A.x));
  D.y = nv7;
  A.x = nv0;
}

__global__ __launch_bounds__(64, 1) void circuit_kernel(
    const float* __restrict__ x, const float* __restrict__ W,
    const float* __restrict__ bias, float* __restrict__ out) {
  const int lane = threadIdx.x;
  const int row0 = blockIdx.x * 2;        // this wave owns rows row0, row0+1
  const float4* __restrict__ Wg = (const float4*)W;

  // Register ring: PF pairs x 4 float4 = 160 VGPRs. Pointer induction.
  float4 R[PF][4];
  const float4* pw = Wg + lane;
#pragma unroll
  for (int s = 0; s < PF; ++s) {
    R[s][0] = pw[0];
    R[s][1] = pw[64];
    R[s][2] = pw[128];
    R[s][3] = pw[192];
    pw += 256;
  }

  const float* xr0 = x + row0 * N_WIRES + lane * 8;
  float4 x0a = *(const float4*)(xr0);
  float4 x0b = *(const float4*)(xr0 + 4);
  float4 x1a = *(const float4*)(xr0 + N_WIRES);
  float4 x1b = *(const float4*)(xr0 + N_WIRES + 4);
  float2 A0 = make_float2(x0a.x, x0a.y), B0 = make_float2(x0a.z, x0a.w);
  float2 C0 = make_float2(x0b.x, x0b.y), D0 = make_float2(x0b.z, x0b.w);
  float2 A1 = make_float2(x1a.x, x1a.y), B1 = make_float2(x1a.z, x1a.w);
  float2 C1 = make_float2(x1b.x, x1b.y), D1 = make_float2(x1b.z, x1b.w);

  for (int blk = 0; blk < (PAIRS / PF) - 1; ++blk) {   // 50 iterations
#pragma unroll
    for (int s = 0; s < PF; ++s) {
      // outstanding = 40 table loads (+4 x-loads first iter); retire oldest pair.
      wait_vm<36>();
      pair_compute(A0, B0, C0, D0, R[s][0], R[s][1], R[s][2], R[s][3]);
      pair_compute(A1, B1, C1, D1, R[s][0], R[s][1], R[s][2], R[s][3]);
      R[s][0] = pw[0];
      R[s][1] = pw[64];
      R[s][2] = pw[128];
      R[s][3] = pw[192];
      pw += 256;
    }
  }

  // Drain: pairs 500..509 already in ring; one full wait.
  wait_vm<0>();
#pragma unroll
  for (int s = 0; s < PF; ++s) {
    pair_compute(A0, B0, C0, D0, R[s][0], R[s][1], R[s][2], R[s][3]);
    pair_compute(A1, B1, C1, D1, R[s][0], R[s][1], R[s][2], R[s][3]);
  }

  // Final even layer t = 1020 (block p=510, q0/q1, plain (c,s), pre-masked).
  float4 f0 = Wg[FINAL4 + lane];
  float4 f1 = Wg[FINAL4 + 64 + lane];
  A0 = gate_pk(make_float2(f0.x, f0.y), A0);
  B0 = gate_pk(make_float2(f0.z, f0.w), B0);
  C0 = gate_pk(make_float2(f1.x, f1.y), C0);
  D0 = gate_pk(make_float2(f1.z, f1.w), D0);
  A1 = gate_pk(make_float2(f0.x, f0.y), A1);
  B1 = gate_pk(make_float2(f0.z, f0.w), B1);
  C1 = gate_pk(make_float2(f1.x, f1.y), C1);
  D1 = gate_pk(make_float2(f1.z, f1.w), D1);

  const float* br = bias + lane * 8;
  float4 b0 = *(const float4*)(br);
  float4 b1 = *(const float4*)(br + 4);
  float* orow0 = out + row0 * N_WIRES + lane * 8;
  float4 o00 = {A0.x + b0.x, A0.y + b0.y, B0.x + b0.z, B0.y + b0.w};
  float4 o01 = {C0.x + b1.x, C0.y + b1.y, D0.x + b1.z, D0.y + b1.w};
  *(float4*)(orow0) = o00;
  *(float4*)(orow0 + 4) = o01;
  float* orow1 = orow0 + N_WIRES;
  float4 o10 = {A1.x + b0.x, A1.y + b0.y, B1.x + b0.z, B1.y + b0.w};
  float4 o11 = {C1.x + b1.x, C1.y + b1.y, D1.x + b1.z, D1.y + b1.w};
  *(float4*)(orow1) = o10;
  *(float4*)(orow1 + 4) = o11;
}

extern "C" void kernel_launch(void* const* d_in, const int* in_sizes, int n_in,
                              void* d_out, int out_size, void* d_ws,
                              size_t ws_size, hipStream_t stream) {
  const float* x = (const float*)d_in[0];       // (256, 512) f32
  const float* thetas = (const float*)d_in[1];  // (130816,) f32
  const float* bias = (const float*)d_in[2];    // (512,) f32
  float* out = (float*)d_out;                   // (256, 512) f32

  float* W = (float*)d_ws;                      // 130688 float4 = 2,091,008 B

  fused_kernel<<<(TOTAL2 + 255) / 256, 256, 0, stream>>>(thetas, (float2*)W);
  circuit_kernel<<<BATCH / 2, 64, 0, stream>>>(x, W, bias, out);
}